// Round 4
// baseline (121.959 us; speedup 1.0000x reference)
//
#include <hip/hip_runtime.h>

#define B 16
#define L 2048
#define D 512
#define MAXC 1025  // L/2 + 1

// ---------------------------------------------------------------------------
// K1: w[row] = sigmoid(dot(xs[row,:], w_lin) + b0), row in [0, B*L)
// One 64-lane wave per row; each lane loads 2 x float4 (covers 512 floats).
// ---------------------------------------------------------------------------
__global__ __launch_bounds__(256) void k_weights(const float* __restrict__ xs,
                                                 const float* __restrict__ w_lin,
                                                 const float* __restrict__ b_lin,
                                                 float* __restrict__ w_out) {
    const int wave = threadIdx.x >> 6;
    const int lane = threadIdx.x & 63;
    const int row = blockIdx.x * 4 + wave;
    if (row >= B * L) return;

    const float4* x4  = (const float4*)(xs + (size_t)row * D);
    const float4* wl4 = (const float4*)w_lin;

    float4 a0 = x4[lane];
    float4 c0 = wl4[lane];
    float p = a0.x * c0.x + a0.y * c0.y + a0.z * c0.z + a0.w * c0.w;
    float4 a1 = x4[lane + 64];
    float4 c1 = wl4[lane + 64];
    p += a1.x * c1.x + a1.y * c1.y + a1.z * c1.z + a1.w * c1.w;

    // 64-lane butterfly reduce
    #pragma unroll
    for (int off = 32; off > 0; off >>= 1) p += __shfl_xor(p, off, 64);

    if (lane == 0) {
        float z = p + b_lin[0];
        w_out[row] = 1.0f / (1.0f + expf(-z));  // accurate expf: minima flips are the risk
    }
}

// ---------------------------------------------------------------------------
// K2: per batch, find strict local minima of w[b,:], build segment lists.
//   starts = [0, m_1, ..., m_k]; ends = [m_1+2, ..., m_k+2, L]; count = k+1
// One block (256 thr) per batch; each thread scans 8 positions; block scan
// assigns minima ordinals. Also writes olens_out as FLOAT values (the harness
// reads the whole d_out buffer as float32 and compares numerically).
// ---------------------------------------------------------------------------
__global__ __launch_bounds__(256) void k_segments(const float* __restrict__ w,
                                                  int* __restrict__ starts,
                                                  int* __restrict__ ends,
                                                  int* __restrict__ count,
                                                  const int* __restrict__ olens,
                                                  float* __restrict__ olens_out) {
    const int b = blockIdx.x;
    const int tid = threadIdx.x;
    const float* wb = w + (size_t)b * L;

    // gather local minima (strict minima can't be adjacent -> <=4 in 8 slots)
    int pos[4];
    int lcnt = 0;
    const int t0 = tid * 8;
    #pragma unroll
    for (int i = 0; i < 8; ++i) {
        int t = t0 + i;
        if (t >= 1 && t <= L - 2) {
            float c = wb[t];
            if (c < wb[t - 1] && c < wb[t + 1]) pos[lcnt++] = t;
        }
    }

    // block inclusive scan of lcnt (Hillis-Steele in LDS)
    __shared__ int scn[256];
    scn[tid] = lcnt;
    __syncthreads();
    #pragma unroll
    for (int s = 1; s < 256; s <<= 1) {
        int v = (tid >= s) ? scn[tid - s] : 0;
        __syncthreads();
        scn[tid] += v;
        __syncthreads();
    }
    const int excl = scn[tid] - lcnt;
    const int total = scn[255];  // total minima k

    for (int i = 0; i < lcnt; ++i) {
        int j = excl + i;  // 0-based minima ordinal
        int t = pos[i];
        starts[b * MAXC + j + 1] = t;
        int e = t + 2;
        ends[b * MAXC + j] = (e < L) ? e : L;
    }
    if (tid == 0) {
        starts[b * MAXC + 0] = 0;
        ends[b * MAXC + total] = L;
        count[b] = total + 1;
        // reference: int(float(olens[b]) / float(olens[0]) * MAXC), stored as
        // a float32 NUMBER (harness reads d_out uniformly as float32)
        int v = (int)((float)olens[b] / (float)olens[0] * (float)MAXC);
        olens_out[b] = (float)v;
    }
}

// ---------------------------------------------------------------------------
// K3: one block per output row [b, m]. Pool xs*w over [start, end), divide by
// max(sum w, 1e-6). Rows m >= count[b] are written as exact zeros.
// 128 threads x float4 = 512 floats per row.
// ---------------------------------------------------------------------------
__global__ __launch_bounds__(128) void k_pool(const float* __restrict__ xs,
                                              const float* __restrict__ w,
                                              const int* __restrict__ starts,
                                              const int* __restrict__ ends,
                                              const int* __restrict__ count,
                                              float* __restrict__ out) {
    const int m = blockIdx.x;
    const int b = blockIdx.y;
    const int tid = threadIdx.x;

    float4* out4 = (float4*)(out + (size_t)(b * MAXC + m) * D);

    if (m >= count[b]) {
        out4[tid] = make_float4(0.f, 0.f, 0.f, 0.f);
        return;
    }

    const int s = starts[b * MAXC + m];
    const int e = ends[b * MAXC + m];
    const float* wb = w + (size_t)b * L;
    const float4* x4 = (const float4*)(xs + (size_t)b * L * D);

    float4 acc = make_float4(0.f, 0.f, 0.f, 0.f);
    float dsum = 0.f;
    for (int t = s; t < e; ++t) {
        float wt = wb[t];  // same addr across lanes -> broadcast
        dsum += wt;
        float4 x = x4[(size_t)t * (D / 4) + tid];
        acc.x += x.x * wt;
        acc.y += x.y * wt;
        acc.z += x.z * wt;
        acc.w += x.w * wt;
    }
    float inv = 1.0f / fmaxf(dsum, 1e-6f);
    out4[tid] = make_float4(acc.x * inv, acc.y * inv, acc.z * inv, acc.w * inv);
}

// ---------------------------------------------------------------------------
extern "C" void kernel_launch(void* const* d_in, const int* in_sizes, int n_in,
                              void* d_out, int out_size, void* d_ws, size_t ws_size,
                              hipStream_t stream) {
    const float* xs    = (const float*)d_in[0];
    const float* w_lin = (const float*)d_in[1];
    const float* b_lin = (const float*)d_in[2];
    const int*   olens = (const int*)d_in[3];

    float* out = (float*)d_out;
    float* olens_out = (float*)d_out + (size_t)B * MAXC * D;  // float32 values in tuple tail

    char* ws = (char*)d_ws;
    float* w_buf = (float*)ws;                                  // B*L floats
    int* starts  = (int*)(ws + (size_t)B * L * sizeof(float));  // B*MAXC
    int* ends    = starts + B * MAXC;                           // B*MAXC
    int* count   = ends + B * MAXC;                             // B

    k_weights<<<dim3((B * L) / 4), 256, 0, stream>>>(xs, w_lin, b_lin, w_buf);
    k_segments<<<dim3(B), 256, 0, stream>>>(w_buf, starts, ends, count, olens, olens_out);
    k_pool<<<dim3(MAXC, B), 128, 0, stream>>>(xs, w_buf, starts, ends, count, out);
}